// Round 4
// baseline (134.366 us; speedup 1.0000x reference)
//
#include <hip/hip_runtime.h>
#include <hip/hip_bf16.h>

#define DEV static __device__ __forceinline__

typedef __attribute__((ext_vector_type(8))) short bf16x8;
typedef __attribute__((ext_vector_type(4))) float f32x4;

DEV float sigm(float x) { return 1.0f / (1.0f + __expf(-x)); }

DEV unsigned int pack2bf(float a, float b) {
    unsigned ua = __float_as_uint(a); ua = (ua + 0x7FFF + ((ua >> 16) & 1)) >> 16;
    unsigned ub = __float_as_uint(b); ub = (ub + 0x7FFF + ((ub >> 16) & 1)) >> 16;
    return ua | (ub << 16);
}

// B=2, N=256, Nh=192, D=128, R=20
// Kernel A: s_all = where(is_h, h_emb, pad(s_heavy)); x = glu(rmsnorm(s_all)) @ W_i2 + b_i2
__global__ __launch_bounds__(256) void kA(
    const float* __restrict__ s_heavy, const int* __restrict__ is_h,
    const float* __restrict__ h_emb, const float* __restrict__ norm1_w,
    const float* __restrict__ W_i1, const float* __restrict__ b_i1,
    const float* __restrict__ W_i2, const float* __restrict__ b_i2,
    float* __restrict__ s_all, float* __restrict__ x)
{
    const int bi = blockIdx.x;           // b*256 + i
    const int b = bi >> 8, i = bi & 255;
    const int t = threadIdx.x;           // 256 threads
    __shared__ float y[128];
    __shared__ float o[256];
    __shared__ float h[128];
    __shared__ float red[4];

    float s = 0.f;
    if (t < 128) {
        if (is_h[bi] != 0) s = h_emb[t];
        else if (i < 192) s = s_heavy[(b * 192 + i) * 128 + t];
        s_all[bi * 128 + t] = s;
    }
    float ss = s * s;
    #pragma unroll
    for (int off = 32; off > 0; off >>= 1) ss += __shfl_xor(ss, off, 64);
    if ((t & 63) == 0) red[t >> 6] = ss;
    __syncthreads();
    float v = (red[0] + red[1] + red[2] + red[3]) * (1.0f / 128.0f);
    float inv = rsqrtf(v + 1e-6f);
    if (t < 128) y[t] = s * inv * (1.0f + norm1_w[t]);
    __syncthreads();

    float acc = b_i1[t];
    #pragma unroll 8
    for (int k = 0; k < 128; ++k) acc += y[k] * W_i1[k * 256 + t];
    o[t] = acc;
    __syncthreads();
    if (t < 128) {
        float a = o[t], g = o[t + 128];
        h[t] = a * sigm(a) * sigm(g);
    }
    __syncthreads();
    for (int c = t; c < 384; c += 256) {
        float a2 = b_i2[c];
        #pragma unroll 8
        for (int k = 0; k < 128; ++k) a2 += h[k] * W_i2[k * 384 + c];
        x[(long)bi * 384 + c] = a2;
    }
}

// Kernel B (MFMA): per (b,i): W~ = [rbf*mask | mask] @ [Wf ; bf]  (bf16 MFMA, K=32 padded),
// consumed in-register: val = W~ * x;  dq = sum_j val; dmuR = sum_j val*dir; dmumu = sum_j val*v.
// 512 threads = 8 waves; wave w owns c-tiles {3w,3w+1,3w+2} (c0 = 48w+16u).
__global__ __launch_bounds__(512, 1) void kB_mfma(
    const float* __restrict__ rbf, const float* __restrict__ dir_ij,
    const float* __restrict__ mask_ij, const float* __restrict__ v_all,
    const float* __restrict__ W_filter, const float* __restrict__ b_filter,
    const float* __restrict__ s_all, const float* __restrict__ x,
    float* __restrict__ q, float* __restrict__ mu)
{
    const int bi = blockIdx.x;
    const int b = bi >> 8;
    const int t = threadIdx.x;
    const int lane = t & 63, wv = t >> 6;

    __shared__ unsigned int phi[4096];   // [256 j][16 u32] = 32 bf16 r'
    __shared__ unsigned int wft[6144];   // [384 c][16 u32] = 32 bf16 r'
    __shared__ float dir_t[768];         // [3][256]
    __shared__ float mask_s[256];
    __shared__ float xt[6208];           // [16][388] padded
    __shared__ float vt[6240];           // [16][390] padded
    __shared__ float dmu_merge[384];

    // ---- setup: stage mask, dir ----
    for (int idx = t; idx < 256; idx += 512) mask_s[idx] = mask_ij[(long)bi * 256 + idx];
    for (int idx = t; idx < 768; idx += 512) {
        int r3 = idx >> 8, j = idx & 255;
        dir_t[idx] = dir_ij[(long)bi * 768 + j * 3 + r3];
    }
    __syncthreads();

    // ---- build phi (bf16, mask folded, bias channel, zero pad to 32) ----
    for (int idx = t; idx < 4096; idx += 512) {
        int j = idx >> 4, rp = idx & 15;
        float m = mask_s[j];
        float v0 = 0.f, v1 = 0.f;
        if (rp < 10) {
            const float* rr = rbf + (long)bi * 5120 + j * 20 + rp * 2;
            v0 = rr[0] * m; v1 = rr[1] * m;
        } else if (rp == 10) v0 = m;
        phi[j * 16 + rp] = pack2bf(v0, v1);
    }
    // ---- build wft (transposed W_filter + bias row, bf16) ----
    for (int idx = t; idx < 6144; idx += 512) {
        int rp = idx / 384, c = idx - rp * 384;
        float v0 = 0.f, v1 = 0.f;
        if (rp < 10) { v0 = W_filter[(rp * 2) * 384 + c]; v1 = W_filter[(rp * 2 + 1) * 384 + c]; }
        else if (rp == 10) v0 = b_filter[c];
        wft[c * 16 + rp] = pack2bf(v0, v1);
    }
    __syncthreads();

    // ---- hoist B fragments (j-invariant) ----
    bf16x8 bfr[3];
    #pragma unroll
    for (int u = 0; u < 3; ++u) {
        int c0 = wv * 48 + u * 16;
        bfr[u] = *(const bf16x8*)&wft[(c0 + (lane & 15)) * 16 + (lane >> 4) * 4];
    }

    // ---- precompute LDS staging offsets (tile-invariant) ----
    int xls[12], vls[12];
    #pragma unroll
    for (int k = 0; k < 12; ++k) {
        int idx = k * 512 + t;
        int jr = idx / 384;
        xls[k] = idx + jr * 4;   // stride 388
        vls[k] = idx + jr * 6;   // stride 390
    }
    const float* xg = x + (long)b * 98304;
    const float* vg = v_all + (long)b * 98304;

    // ---- prologue: stage tile 0 ----
    {
        float xr[12], vr[12];
        #pragma unroll
        for (int k = 0; k < 12; ++k) { xr[k] = xg[k * 512 + t]; vr[k] = vg[k * 512 + t]; }
        #pragma unroll
        for (int k = 0; k < 12; ++k) { xt[xls[k]] = xr[k]; vt[vls[k]] = vr[k]; }
    }
    __syncthreads();

    float acc[3][3];
    #pragma unroll
    for (int u = 0; u < 3; ++u)
        #pragma unroll
        for (int r3 = 0; r3 < 3; ++r3) acc[u][r3] = 0.f;

    // ---- main loop over 16 j-tiles ----
    for (int tt = 0; tt < 16; ++tt) {
        float xr[12], vr[12];
        if (tt < 15) {
            const float* xs = xg + (tt + 1) * 6144;
            const float* vs = vg + (tt + 1) * 6144;
            #pragma unroll
            for (int k = 0; k < 12; ++k) { xr[k] = xs[k * 512 + t]; vr[k] = vs[k * 512 + t]; }
        }
        // consume tile tt
        bf16x8 afr = *(const bf16x8*)&phi[(tt * 16 + (lane & 15)) * 16 + (lane >> 4) * 4];
        #pragma unroll
        for (int u = 0; u < 3; ++u) {
            f32x4 dd = {0.f, 0.f, 0.f, 0.f};
            dd = __builtin_amdgcn_mfma_f32_16x16x32_bf16(afr, bfr[u], dd, 0, 0, 0);
            const int c0 = wv * 48 + u * 16;
            const int cc = c0 + (lane & 15);
            #pragma unroll
            for (int e = 0; e < 4; ++e) {
                const int jl = (lane >> 4) * 4 + e;
                float val = dd[e] * xt[jl * 388 + cc];
                if (c0 < 128) {
                    acc[u][0] += val;
                } else if (c0 < 256) {
                    #pragma unroll
                    for (int r3 = 0; r3 < 3; ++r3)
                        acc[u][r3] += val * dir_t[r3 * 256 + tt * 16 + jl];
                } else {
                    #pragma unroll
                    for (int r3 = 0; r3 < 3; ++r3)
                        acc[u][r3] += val * vt[jl * 390 + 128 * r3 + (cc - 256)];
                }
            }
        }
        __syncthreads();
        if (tt < 15) {
            #pragma unroll
            for (int k = 0; k < 12; ++k) { xt[xls[k]] = xr[k]; vt[vls[k]] = vr[k]; }
        }
        __syncthreads();
    }

    // ---- epilogue: cross-rowgroup reduce + writes ----
    #pragma unroll
    for (int u = 0; u < 3; ++u) {
        const int c0 = wv * 48 + u * 16;
        if (c0 < 128) {
            float a = acc[u][0];
            a += __shfl_xor(a, 16, 64); a += __shfl_xor(a, 32, 64);
            if (lane < 16) {
                int c = c0 + lane;
                q[bi * 128 + c] = s_all[bi * 128 + c] + a;
            }
        } else if (c0 < 256) {
            #pragma unroll
            for (int r3 = 0; r3 < 3; ++r3) {
                float a = acc[u][r3];
                a += __shfl_xor(a, 16, 64); a += __shfl_xor(a, 32, 64);
                if (lane < 16) dmu_merge[r3 * 128 + (c0 - 128) + lane] = a;
            }
        }
    }
    __syncthreads();
    #pragma unroll
    for (int u = 0; u < 3; ++u) {
        const int c0 = wv * 48 + u * 16;
        if (c0 >= 256) {
            #pragma unroll
            for (int r3 = 0; r3 < 3; ++r3) {
                float a = acc[u][r3];
                a += __shfl_xor(a, 16, 64); a += __shfl_xor(a, 32, 64);
                if (lane < 16) {
                    int d = (c0 - 256) + lane;
                    mu[(long)bi * 384 + r3 * 128 + d] =
                        v_all[(long)bi * 384 + r3 * 128 + d] + dmu_merge[r3 * 128 + d] + a;
                }
            }
        }
    }
}

// Kernel C: mixing. mu_mix = mu @ W_mu; ctx = [rmsnorm(q), |mu_V|]; GLU; epilogue.
__global__ __launch_bounds__(256) void kC(
    const float* __restrict__ W_mu, const float* __restrict__ norm2_w,
    const float* __restrict__ W_m1, const float* __restrict__ b_m1,
    const float* __restrict__ W_m2, const float* __restrict__ b_m2,
    const float* __restrict__ q, const float* __restrict__ mu,
    float* __restrict__ q_out, float* __restrict__ mu_out)
{
    const int bi = blockIdx.x;
    const int b = bi >> 8, i = bi & 255;
    const int t = threadIdx.x;  // 256
    __shared__ float mu_s[384];
    __shared__ float muV[384], muW[384];
    __shared__ float ctx[256];
    __shared__ float o[256];
    __shared__ float h[128];
    __shared__ float x2s[384];
    __shared__ float red[4];

    for (int idx = t; idx < 384; idx += 256) mu_s[idx] = mu[(long)bi * 384 + idx];
    __syncthreads();

    float m0 = 0.f, m1 = 0.f, m2 = 0.f;
    #pragma unroll 8
    for (int k = 0; k < 128; ++k) {
        float w = W_mu[k * 256 + t];
        m0 += mu_s[k] * w;
        m1 += mu_s[128 + k] * w;
        m2 += mu_s[256 + k] * w;
    }
    if (t < 128) { muV[t] = m0; muV[128 + t] = m1; muV[256 + t] = m2; }
    else { int d2 = t - 128; muW[d2] = m0; muW[128 + d2] = m1; muW[256 + d2] = m2; }

    float qv = 0.f;
    if (t < 128) qv = q[bi * 128 + t];
    float ss = qv * qv;
    #pragma unroll
    for (int off = 32; off > 0; off >>= 1) ss += __shfl_xor(ss, off, 64);
    if ((t & 63) == 0) red[t >> 6] = ss;
    __syncthreads();
    float mean = (red[0] + red[1] + red[2] + red[3]) * (1.0f / 128.0f);
    if (t < 128) {
        ctx[t] = qv * rsqrtf(mean + 1e-6f) * (1.0f + norm2_w[t]);
    } else {
        int d2 = t - 128;
        ctx[t] = sqrtf(muV[d2] * muV[d2] + muV[128 + d2] * muV[128 + d2]
                       + muV[256 + d2] * muV[256 + d2] + 1e-6f);
    }
    __syncthreads();

    float acc = b_m1[t];
    #pragma unroll 8
    for (int k = 0; k < 256; ++k) acc += ctx[k] * W_m1[k * 256 + t];
    o[t] = acc;
    __syncthreads();
    if (t < 128) { float a = o[t], g = o[t + 128]; h[t] = a * sigm(a) * sigm(g); }
    __syncthreads();
    for (int c = t; c < 384; c += 256) {
        float a2 = b_m2[c];
        #pragma unroll 8
        for (int k = 0; k < 128; ++k) a2 += h[k] * W_m2[k * 384 + c];
        x2s[c] = a2;
    }
    __syncthreads();

    if (t < 128) {
        const int d = t;
        float vw = muV[d] * muW[d] + muV[128 + d] * muW[128 + d] + muV[256 + d] * muW[256 + d];
        if (i < 192)
            q_out[((long)b * 192 + i) * 128 + d] = qv + x2s[d] + x2s[256 + d] * vw;
        #pragma unroll
        for (int r = 0; r < 3; ++r)
            mu_out[((long)bi * 3 + r) * 128 + d] =
                mu_s[r * 128 + d] + x2s[128 + d] * muW[r * 128 + d];
    }
}

extern "C" void kernel_launch(void* const* d_in, const int* in_sizes, int n_in,
                              void* d_out, int out_size, void* d_ws, size_t ws_size,
                              hipStream_t stream) {
    (void)in_sizes; (void)n_in; (void)out_size; (void)ws_size;
    const float* s_heavy  = (const float*)d_in[0];
    const float* v_all    = (const float*)d_in[1];
    const float* rbf      = (const float*)d_in[2];
    const float* dir_ij   = (const float*)d_in[3];
    const float* mask_ij  = (const float*)d_in[4];
    const int*   is_h     = (const int*)d_in[5];
    const float* h_emb    = (const float*)d_in[6];
    const float* W_filter = (const float*)d_in[7];
    const float* b_filter = (const float*)d_in[8];
    const float* norm1_w  = (const float*)d_in[9];
    const float* W_i1     = (const float*)d_in[10];
    const float* b_i1     = (const float*)d_in[11];
    const float* W_i2     = (const float*)d_in[12];
    const float* b_i2     = (const float*)d_in[13];
    const float* norm2_w  = (const float*)d_in[14];
    const float* W_m1     = (const float*)d_in[15];
    const float* b_m1     = (const float*)d_in[16];
    const float* W_m2     = (const float*)d_in[17];
    const float* b_m2     = (const float*)d_in[18];
    const float* W_mu     = (const float*)d_in[19];

    float* ws    = (float*)d_ws;
    float* s_all = ws;               // 2*256*128        = 65536 floats
    float* x     = ws + 65536;       // 2*256*384        = 196608 floats
    float* q     = ws + 262144;      // 2*256*128        = 65536 floats
    float* mu    = ws + 327680;      // 2*256*3*128      = 196608 floats

    float* q_out  = (float*)d_out;               // (2,192,128)
    float* mu_out = q_out + 2 * 192 * 128;       // (2,256,3,128)

    kA<<<512, 256, 0, stream>>>(s_heavy, is_h, h_emb, norm1_w, W_i1, b_i1, W_i2, b_i2,
                                s_all, x);
    kB_mfma<<<512, 512, 0, stream>>>(rbf, dir_ij, mask_ij, v_all, W_filter, b_filter,
                                     s_all, x, q, mu);
    kC<<<512, 256, 0, stream>>>(W_mu, norm2_w, W_m1, b_m1, W_m2, b_m2,
                                q, mu, q_out, mu_out);
}

// Round 5
// 96.127 us; speedup vs baseline: 1.3978x; 1.3978x over previous
//
#include <hip/hip_runtime.h>
#include <hip/hip_bf16.h>

#define DEV static __device__ __forceinline__

typedef __attribute__((ext_vector_type(8))) short bf16x8;
typedef __attribute__((ext_vector_type(4))) float f32x4;

DEV float sigm(float x) { return 1.0f / (1.0f + __expf(-x)); }

DEV unsigned pack2bf(float a, float b) {
    unsigned ua = __float_as_uint(a); ua = (ua + 0x7FFF + ((ua >> 16) & 1)) >> 16;
    unsigned ub = __float_as_uint(b); ub = (ub + 0x7FFF + ((ub >> 16) & 1)) >> 16;
    return ua | (ub << 16);
}

// B=2, N=256, Nh=192, D=128, R=20
// Kernel A: s_all = where(is_h, h_emb, pad(s_heavy)); x = glu(rmsnorm(s_all)) @ W_i2 + b_i2
__global__ __launch_bounds__(256) void kA(
    const float* __restrict__ s_heavy, const int* __restrict__ is_h,
    const float* __restrict__ h_emb, const float* __restrict__ norm1_w,
    const float* __restrict__ W_i1, const float* __restrict__ b_i1,
    const float* __restrict__ W_i2, const float* __restrict__ b_i2,
    float* __restrict__ s_all, float* __restrict__ x)
{
    const int bi = blockIdx.x;
    const int b = bi >> 8, i = bi & 255;
    const int t = threadIdx.x;
    __shared__ float y[128];
    __shared__ float o[256];
    __shared__ float h[128];
    __shared__ float red[4];

    float s = 0.f;
    if (t < 128) {
        if (is_h[bi] != 0) s = h_emb[t];
        else if (i < 192) s = s_heavy[(b * 192 + i) * 128 + t];
        s_all[bi * 128 + t] = s;
    }
    float ss = s * s;
    #pragma unroll
    for (int off = 32; off > 0; off >>= 1) ss += __shfl_xor(ss, off, 64);
    if ((t & 63) == 0) red[t >> 6] = ss;
    __syncthreads();
    float v = (red[0] + red[1] + red[2] + red[3]) * (1.0f / 128.0f);
    float inv = rsqrtf(v + 1e-6f);
    if (t < 128) y[t] = s * inv * (1.0f + norm1_w[t]);
    __syncthreads();

    float acc = b_i1[t];
    #pragma unroll 8
    for (int k = 0; k < 128; ++k) acc += y[k] * W_i1[k * 256 + t];
    o[t] = acc;
    __syncthreads();
    if (t < 128) {
        float a = o[t], g = o[t + 128];
        h[t] = a * sigm(a) * sigm(g);
    }
    __syncthreads();
    for (int c = t; c < 384; c += 256) {
        float a2 = b_i2[c];
        #pragma unroll 8
        for (int k = 0; k < 128; ++k) a2 += h[k] * W_i2[k * 384 + c];
        x[(long)bi * 384 + c] = a2;
    }
}

// Kernel X: build B-panel Bg[b][col][k=j] bf16 (u32-packed pairs), col<256: x; col>=256: v*x.
__global__ __launch_bounds__(256) void kX(
    const float* __restrict__ x, const float* __restrict__ v_all,
    unsigned* __restrict__ Bg)
{
    const int blk = blockIdx.x;          // 80 = 2 b * 40 coltiles
    const int b = blk / 40, ct = blk % 40;
    const int c0 = ct * 16;
    const int t = threadIdx.x;
    __shared__ float lt[32][17];
    const float* xb = x + (long)b * 98304;
    const float* vb = v_all + (long)b * 98304;
    const int col_w = t >> 4, j2 = t & 15;
    for (int pass = 0; pass < 8; ++pass) {
        const int j0 = pass * 32;
        #pragma unroll
        for (int rep = 0; rep < 2; ++rep) {
            int idx = rep * 256 + t;
            int jj = idx >> 4, cc = idx & 15;
            int j = j0 + jj;
            float val;
            if (c0 < 256) {
                val = xb[j * 384 + c0 + cc];
            } else {
                int cg = c0 - 256 + cc;
                int r3 = cg >> 7, c3 = cg & 127;
                val = vb[j * 384 + r3 * 128 + c3] * xb[j * 384 + 256 + c3];
            }
            lt[jj][cc] = val;
        }
        __syncthreads();
        unsigned p = pack2bf(lt[2 * j2][col_w], lt[2 * j2 + 1][col_w]);
        Bg[((long)(b * 640 + c0 + col_w)) * 128 + (j0 >> 1) + j2] = p;
        __syncthreads();
    }
}

// Kernel B2: per (b,i): A (96 x 256 bf16, LDS) @ Bg (256 x 640 bf16, global/L2) via MFMA;
// in-register Wf contraction epilogue -> q, mu.  512 thr = 8 waves.
// Rows: 0-19 rbf*m, 20 m, 21-31 zero, 32+idx (idx=r3*21+r): rbf*m*dir (r=20 -> m*dir), 95 zero.
// Wave w<2: T1 tiles (rt 0-1, ct 4w+ci) -> dq.  w>=2: T3 (rt 0-1, ct 4w+8+ci) -> dmumu.
// All waves: T2 (rt 2-5, ct 8+w) -> dmuR.
__global__ __launch_bounds__(512, 4) void kB2(
    const float* __restrict__ rbf, const float* __restrict__ dir_ij,
    const float* __restrict__ mask_ij, const float* __restrict__ v_all,
    const float* __restrict__ W_filter, const float* __restrict__ b_filter,
    const float* __restrict__ s_all, const unsigned* __restrict__ Bg,
    float* __restrict__ q, float* __restrict__ mu)
{
    const int bi = blockIdx.x, b = bi >> 8;
    const int t = threadIdx.x;
    const int lane = t & 63, w = t >> 6, g = lane >> 4, l16 = lane & 15;

    __shared__ unsigned A_lds[96 * 132];   // 96 rows x 264 bf16 (k pad for banks)
    __shared__ float rbf_s[5120];
    __shared__ float dir_s[768];
    __shared__ float m_s[256];
    __shared__ float dmuR_s[384];
    __shared__ float dmumu_s[384];

    for (int i2 = t; i2 < 5120; i2 += 512) rbf_s[i2] = rbf[(long)bi * 5120 + i2];
    for (int i2 = t; i2 < 768; i2 += 512) dir_s[i2] = dir_ij[(long)bi * 768 + i2];
    for (int i2 = t; i2 < 256; i2 += 512) m_s[i2] = mask_ij[(long)bi * 256 + i2];
    __syncthreads();

    // ---- build A (bf16 pairs) ----
    for (int e = t; e < 96 * 128; e += 512) {
        int row = e >> 7, j2 = e & 127;
        float v01[2];
        #pragma unroll
        for (int u = 0; u < 2; ++u) {
            int j = 2 * j2 + u;
            float val = 0.f;
            if (row < 20) val = rbf_s[j * 20 + row] * m_s[j];
            else if (row == 20) val = m_s[j];
            else if (row >= 32) {
                int idx = row - 32;
                if (idx < 63) {
                    int r3 = (idx >= 42) ? 2 : ((idx >= 21) ? 1 : 0);
                    int r = idx - 21 * r3;
                    float base = (r < 20) ? rbf_s[j * 20 + r] : 1.f;
                    val = base * m_s[j] * dir_s[j * 3 + r3];
                }
            }
            v01[u] = val;
        }
        A_lds[row * 132 + j2] = pack2bf(v01[0], v01[1]);
    }
    __syncthreads();

    // ---- tile assignment ----
    int colR[4];
    #pragma unroll
    for (int ci = 0; ci < 4; ++ci) {
        int ct = (w < 2) ? (4 * w + ci) : (4 * w + 8 + ci);
        colR[ci] = ct * 16 + l16;
    }
    const int col2 = (8 + w) * 16 + l16;

    const unsigned* BgB = Bg + (long)b * 640 * 128;
    const unsigned* Bp[5];
    #pragma unroll
    for (int ci = 0; ci < 4; ++ci) Bp[ci] = BgB + (long)colR[ci] * 128;
    Bp[4] = BgB + (long)col2 * 128;

    f32x4 accR[4][2];
    f32x4 acc2[4];
    #pragma unroll
    for (int ci = 0; ci < 4; ++ci) {
        #pragma unroll
        for (int rt = 0; rt < 2; ++rt) accR[ci][rt] = {0.f, 0.f, 0.f, 0.f};
        acc2[ci] = {0.f, 0.f, 0.f, 0.f};
    }

    // ---- GEMM: K = 256 = 8 k-steps of 32 ----
    #pragma unroll 2
    for (int kt = 0; kt < 8; ++kt) {
        bf16x8 af[6];
        #pragma unroll
        for (int rt = 0; rt < 6; ++rt)
            af[rt] = *(const bf16x8*)&A_lds[(rt * 16 + l16) * 132 + kt * 16 + g * 4];
        bf16x8 bfr[5];
        #pragma unroll
        for (int u = 0; u < 5; ++u)
            bfr[u] = *(const bf16x8*)&Bp[u][kt * 16 + g * 4];
        #pragma unroll
        for (int ci = 0; ci < 4; ++ci) {
            accR[ci][0] = __builtin_amdgcn_mfma_f32_16x16x32_bf16(af[0], bfr[ci], accR[ci][0], 0, 0, 0);
            accR[ci][1] = __builtin_amdgcn_mfma_f32_16x16x32_bf16(af[1], bfr[ci], accR[ci][1], 0, 0, 0);
        }
        #pragma unroll
        for (int rt = 0; rt < 4; ++rt)
            acc2[rt] = __builtin_amdgcn_mfma_f32_16x16x32_bf16(af[2 + rt], bfr[4], acc2[rt], 0, 0, 0);
    }

    // ---- epilogue T2 -> dmuR ----
    {
        float p3[3] = {0.f, 0.f, 0.f};
        const int c = 128 + 16 * w + l16;
        #pragma unroll
        for (int rt = 0; rt < 4; ++rt) {
            #pragma unroll
            for (int e = 0; e < 4; ++e) {
                int l = rt * 16 + g * 4 + e;
                if (l < 63) {
                    int r3 = (l >= 42) ? 2 : ((l >= 21) ? 1 : 0);
                    int rr = l - 21 * r3;
                    float wgt = (rr < 20) ? W_filter[rr * 384 + c] : b_filter[c];
                    p3[r3] += wgt * acc2[rt][e];
                }
            }
        }
        #pragma unroll
        for (int r3 = 0; r3 < 3; ++r3) {
            float a = p3[r3];
            a += __shfl_xor(a, 16, 64);
            a += __shfl_xor(a, 32, 64);
            if (lane < 16) dmuR_s[r3 * 128 + 16 * w + l16] = a;
        }
    }

    // ---- epilogue T1/T3 -> dq / dmumu ----
    #pragma unroll
    for (int ci = 0; ci < 4; ++ci) {
        const int cwf = (w < 2) ? colR[ci] : (256 + ((colR[ci] - 256) & 127));
        float p = 0.f;
        #pragma unroll
        for (int rt = 0; rt < 2; ++rt) {
            #pragma unroll
            for (int e = 0; e < 4; ++e) {
                int row = rt * 16 + g * 4 + e;
                if (row <= 20) {
                    float wgt = (row < 20) ? W_filter[row * 384 + cwf] : b_filter[cwf];
                    p += wgt * accR[ci][rt][e];
                }
            }
        }
        p += __shfl_xor(p, 16, 64);
        p += __shfl_xor(p, 32, 64);
        if (lane < 16) {
            if (w < 2) {
                int c = colR[ci];
                q[bi * 128 + c] = s_all[bi * 128 + c] + p;
            } else {
                dmumu_s[colR[ci] - 256] = p;
            }
        }
    }
    __syncthreads();
    for (int e2 = t; e2 < 384; e2 += 512)
        mu[(long)bi * 384 + e2] = v_all[(long)bi * 384 + e2] + dmuR_s[e2] + dmumu_s[e2];
}

// Kernel C: mixing. mu_mix = mu @ W_mu; ctx = [rmsnorm(q), |mu_V|]; GLU; epilogue.
__global__ __launch_bounds__(256) void kC(
    const float* __restrict__ W_mu, const float* __restrict__ norm2_w,
    const float* __restrict__ W_m1, const float* __restrict__ b_m1,
    const float* __restrict__ W_m2, const float* __restrict__ b_m2,
    const float* __restrict__ q, const float* __restrict__ mu,
    float* __restrict__ q_out, float* __restrict__ mu_out)
{
    const int bi = blockIdx.x;
    const int b = bi >> 8, i = bi & 255;
    const int t = threadIdx.x;
    __shared__ float mu_s[384];
    __shared__ float muV[384], muW[384];
    __shared__ float ctx[256];
    __shared__ float o[256];
    __shared__ float h[128];
    __shared__ float x2s[384];
    __shared__ float red[4];

    for (int idx = t; idx < 384; idx += 256) mu_s[idx] = mu[(long)bi * 384 + idx];
    __syncthreads();

    float m0 = 0.f, m1 = 0.f, m2 = 0.f;
    #pragma unroll 8
    for (int k = 0; k < 128; ++k) {
        float ww = W_mu[k * 256 + t];
        m0 += mu_s[k] * ww;
        m1 += mu_s[128 + k] * ww;
        m2 += mu_s[256 + k] * ww;
    }
    if (t < 128) { muV[t] = m0; muV[128 + t] = m1; muV[256 + t] = m2; }
    else { int d2 = t - 128; muW[d2] = m0; muW[128 + d2] = m1; muW[256 + d2] = m2; }

    float qv = 0.f;
    if (t < 128) qv = q[bi * 128 + t];
    float ss = qv * qv;
    #pragma unroll
    for (int off = 32; off > 0; off >>= 1) ss += __shfl_xor(ss, off, 64);
    if ((t & 63) == 0) red[t >> 6] = ss;
    __syncthreads();
    float mean = (red[0] + red[1] + red[2] + red[3]) * (1.0f / 128.0f);
    if (t < 128) {
        ctx[t] = qv * rsqrtf(mean + 1e-6f) * (1.0f + norm2_w[t]);
    } else {
        int d2 = t - 128;
        ctx[t] = sqrtf(muV[d2] * muV[d2] + muV[128 + d2] * muV[128 + d2]
                       + muV[256 + d2] * muV[256 + d2] + 1e-6f);
    }
    __syncthreads();

    float acc = b_m1[t];
    #pragma unroll 8
    for (int k = 0; k < 256; ++k) acc += ctx[k] * W_m1[k * 256 + t];
    o[t] = acc;
    __syncthreads();
    if (t < 128) { float a = o[t], gg = o[t + 128]; h[t] = a * sigm(a) * sigm(gg); }
    __syncthreads();
    for (int c = t; c < 384; c += 256) {
        float a2 = b_m2[c];
        #pragma unroll 8
        for (int k = 0; k < 128; ++k) a2 += h[k] * W_m2[k * 384 + c];
        x2s[c] = a2;
    }
    __syncthreads();

    if (t < 128) {
        const int d = t;
        float vw = muV[d] * muW[d] + muV[128 + d] * muW[128 + d] + muV[256 + d] * muW[256 + d];
        if (i < 192)
            q_out[((long)b * 192 + i) * 128 + d] = qv + x2s[d] + x2s[256 + d] * vw;
        #pragma unroll
        for (int r = 0; r < 3; ++r)
            mu_out[((long)bi * 3 + r) * 128 + d] =
                mu_s[r * 128 + d] + x2s[128 + d] * muW[r * 128 + d];
    }
}

extern "C" void kernel_launch(void* const* d_in, const int* in_sizes, int n_in,
                              void* d_out, int out_size, void* d_ws, size_t ws_size,
                              hipStream_t stream) {
    (void)in_sizes; (void)n_in; (void)out_size; (void)ws_size;
    const float* s_heavy  = (const float*)d_in[0];
    const float* v_all    = (const float*)d_in[1];
    const float* rbf      = (const float*)d_in[2];
    const float* dir_ij   = (const float*)d_in[3];
    const float* mask_ij  = (const float*)d_in[4];
    const int*   is_h     = (const int*)d_in[5];
    const float* h_emb    = (const float*)d_in[6];
    const float* W_filter = (const float*)d_in[7];
    const float* b_filter = (const float*)d_in[8];
    const float* norm1_w  = (const float*)d_in[9];
    const float* W_i1     = (const float*)d_in[10];
    const float* b_i1     = (const float*)d_in[11];
    const float* W_i2     = (const float*)d_in[12];
    const float* b_i2     = (const float*)d_in[13];
    const float* norm2_w  = (const float*)d_in[14];
    const float* W_m1     = (const float*)d_in[15];
    const float* b_m1     = (const float*)d_in[16];
    const float* W_m2     = (const float*)d_in[17];
    const float* b_m2     = (const float*)d_in[18];
    const float* W_mu     = (const float*)d_in[19];

    float* ws    = (float*)d_ws;
    float* s_all = ws;                       // 65536 f
    float* x     = ws + 65536;               // 196608 f
    float* q     = ws + 262144;              // 65536 f
    float* mu    = ws + 327680;              // 196608 f
    unsigned* Bg = (unsigned*)(ws + 524288); // 2*640*128 u32 = 163840

    float* q_out  = (float*)d_out;               // (2,192,128)
    float* mu_out = q_out + 2 * 192 * 128;       // (2,256,3,128)

    kA<<<512, 256, 0, stream>>>(s_heavy, is_h, h_emb, norm1_w, W_i1, b_i1, W_i2, b_i2,
                                s_all, x);
    kX<<<80, 256, 0, stream>>>(x, v_all, Bg);
    kB2<<<512, 512, 0, stream>>>(rbf, dir_ij, mask_ij, v_all, W_filter, b_filter,
                                 s_all, Bg, q, mu);
    kC<<<512, 256, 0, stream>>>(W_mu, norm2_w, W_m1, b_m1, W_m2, b_m2,
                                q, mu, q_out, mu_out);
}